// Round 3
// baseline (867.578 us; speedup 1.0000x reference)
//
#include <hip/hip_runtime.h>

#define BATCH 65536
#define NF 16

typedef unsigned short u16;
typedef unsigned int u32;
typedef __bf16 bf16x8 __attribute__((ext_vector_type(8)));
typedef float f32x4 __attribute__((ext_vector_type(4)));

union Frag { bf16x8 v; u16 s[8]; };

__device__ __forceinline__ u16 f2bf(float f) {
  u32 u;
  __builtin_memcpy(&u, &f, 4);
  u = (u + 0x7fffu + ((u >> 16) & 1u)) >> 16;  // round-to-nearest-even
  return (u16)u;
}

__device__ __forceinline__ float tanh_fast(float v) {
  // tanh(v) = 1 - 2/(exp(2v)+1); rcp(inf)=0 makes the +/-large cases exact
  float e = __expf(v + v);
  return 1.0f - 2.0f * __builtin_amdgcn_rcpf(e + 1.0f);
}

// Block = 64 batch rows, 256 threads (4 waves). Wave w owns n-tiles {2w,2w+1}
// (N padded 100->128). B-fragments (W^T, fp32->bf16) live in registers; the
// matmul input u round-trips through LDS in MFMA A-fragment layout.
// LDS A-layout: element (row r64 in 0..63, col c in 0..127) at
//   idx8 = (c>>3)*65 + r64   (pad 64->65 kills write bank conflicts)
//   elem = idx8*8 + (c&7)
__global__ __launch_bounds__(256) void node_kernel(
    const float* __restrict__ x,
    const float* __restrict__ W0, const float* __restrict__ b0,
    const float* __restrict__ W1, const float* __restrict__ b1,
    const float* __restrict__ Wode, const float* __restrict__ bode,
    float* __restrict__ out)
{
  __shared__ __align__(16) u16 Au[8320];

  const int tid  = threadIdx.x;
  const int lane = tid & 63;
  const int w    = tid >> 6;   // wave 0..3
  const int col  = lane & 15;
  const int quad = lane >> 4;
  const int rowBase = blockIdx.x * 64;

  const float dt  = 1.0f / 15.0f;
  const float dt3 = dt / 3.0f;
  const float e8  = dt * 0.125f;
  const float q8  = dt * dt * 0.125f;

  int cc[2];
  cc[0] = (w * 2) * 16 + col;
  cc[1] = cc[0] + 16;

  int abase[2];   // LDS element-index base for scatter writes (this lane's col)
  int obase[2];   // global out element base
#pragma unroll
  for (int n2 = 0; n2 < 2; ++n2) {
    abase[n2] = ((cc[n2] >> 3) * 65 + quad * 4) * 8 + (cc[n2] & 7);
    obase[n2] = (rowBase + quad * 4) * (NF * 100) + cc[n2];
  }

  const int kbase = quad * 8;

  // ---- stage x into LDS (coalesced fp32 reads -> bf16 A-layout), pad=0 ----
#pragma unroll 1
  for (int i = tid; i < 8192; i += 256) {
    int r64 = i >> 7;
    int c   = i & 127;
    float v = (c < 100) ? x[(rowBase + r64) * 100 + c] : 0.0f;
    Au[((c >> 3) * 65 + r64) * 8 + (c & 7)] = f2bf(v);
  }

  // ---- W0/W1 B-fragments + biases (registers) ----
  Frag bf0[2][4], bf1[2][4];
  float bias0[2], bias1[2];
#pragma unroll
  for (int n2 = 0; n2 < 2; ++n2) {
    int n = cc[n2];
    bias0[n2] = (n < 100) ? b0[n] : 0.0f;
    bias1[n2] = (n < 100) ? b1[n] : 0.0f;
#pragma unroll
    for (int kc = 0; kc < 4; ++kc) {
#pragma unroll
      for (int j = 0; j < 8; ++j) {
        int k = kc * 32 + kbase + j;
        bool ok = (n < 100) && (k < 100);
        bf0[n2][kc].s[j] = ok ? f2bf(W0[n * 100 + k]) : (u16)0;
        bf1[n2][kc].s[j] = ok ? f2bf(W1[n * 100 + k]) : (u16)0;
      }
    }
  }

  // ---- W_ode B-fragments + bias ----
  Frag bfo[2][4];
  float biaso[2];
#pragma unroll
  for (int n2 = 0; n2 < 2; ++n2) {
    int n = cc[n2];
    biaso[n2] = (n < 100) ? bode[n] : 0.0f;
#pragma unroll
    for (int kc = 0; kc < 4; ++kc) {
#pragma unroll
      for (int j = 0; j < 8; ++j) {
        int k = kc * 32 + kbase + j;
        bool ok = (n < 100) && (k < 100);
        bfo[n2][kc].s[j] = ok ? f2bf(Wode[n * 100 + k]) : (u16)0;
      }
    }
  }

  __syncthreads();  // x staging visible

  // ---- init: y0 = x@W0^T + b0 ; y1 = x@W1^T + b1 (A-frags from LDS) ----
  float y0a[4][2][4], y1a[4][2][4];
#pragma unroll
  for (int rt = 0; rt < 4; ++rt) {
    bf16x8 af[4];
#pragma unroll
    for (int kc = 0; kc < 4; ++kc)
      af[kc] = *(const bf16x8*)&Au[((kc * 4 + quad) * 65 + rt * 16 + col) * 8];
#pragma unroll
    for (int n2 = 0; n2 < 2; ++n2) {
      f32x4 a0 = { bias0[n2], bias0[n2], bias0[n2], bias0[n2] };
      f32x4 a1 = { bias1[n2], bias1[n2], bias1[n2], bias1[n2] };
#pragma unroll
      for (int kc = 0; kc < 4; ++kc) {
        a0 = __builtin_amdgcn_mfma_f32_16x16x32_bf16(af[kc], bf0[n2][kc].v, a0, 0, 0, 0);
        a1 = __builtin_amdgcn_mfma_f32_16x16x32_bf16(af[kc], bf1[n2][kc].v, a1, 0, 0, 0);
      }
#pragma unroll
      for (int r = 0; r < 4; ++r) { y0a[rt][n2][r] = a0[r]; y1a[rt][n2][r] = a1[r]; }
    }
  }

  __syncthreads();  // init A-reads done; safe to overwrite u

  // ---- seed LDS with u = y0; store t=0 output (= s1) ----
#pragma unroll
  for (int rt = 0; rt < 4; ++rt)
#pragma unroll
    for (int n2 = 0; n2 < 2; ++n2)
#pragma unroll
      for (int r = 0; r < 4; ++r) {
        Au[abase[n2] + rt * 128 + r * 8] = f2bf(y0a[rt][n2][r]);
        if (cc[n2] < 100)
          out[obase[n2] + rt * 25600 + r * 1600] = y1a[rt][n2][r];
      }

  float k1[4][2][4], k2[4][2][4], za[4][2][4];

  auto geval = [&]() {
    __syncthreads();   // u writes visible
#pragma unroll
    for (int rt = 0; rt < 4; ++rt) {
      bf16x8 af[4];
#pragma unroll
      for (int kc = 0; kc < 4; ++kc)
        af[kc] = *(const bf16x8*)&Au[((kc * 4 + quad) * 65 + rt * 16 + col) * 8];
#pragma unroll
      for (int n2 = 0; n2 < 2; ++n2) {
        f32x4 acc = { biaso[n2], biaso[n2], biaso[n2], biaso[n2] };
#pragma unroll
        for (int kc = 0; kc < 4; ++kc)
          acc = __builtin_amdgcn_mfma_f32_16x16x32_bf16(af[kc], bfo[n2][kc].v, acc, 0, 0, 0);
#pragma unroll
        for (int r = 0; r < 4; ++r) za[rt][n2][r] = tanh_fast(acc[r]);
      }
    }
    __syncthreads();   // all A-reads done; safe to overwrite u
  };

#pragma unroll 1
  for (int t = 1; t < NF; ++t) {
    // g1: k1 = g(y0); u2 = y0 + dt/3*k1
    geval();
#pragma unroll
    for (int rt = 0; rt < 4; ++rt)
#pragma unroll
      for (int n2 = 0; n2 < 2; ++n2)
#pragma unroll
        for (int r = 0; r < 4; ++r) {
          float zz = za[rt][n2][r];
          k1[rt][n2][r] = zz;
          Au[abase[n2] + rt * 128 + r * 8] = f2bf(y0a[rt][n2][r] + dt3 * zz);
        }

    // g2: k2 = g(u2); u3 = y0 + dt*k2 - dt/3*k1
    geval();
#pragma unroll
    for (int rt = 0; rt < 4; ++rt)
#pragma unroll
      for (int n2 = 0; n2 < 2; ++n2)
#pragma unroll
        for (int r = 0; r < 4; ++r) {
          float zz = za[rt][n2][r];
          k2[rt][n2][r] = zz;
          Au[abase[n2] + rt * 128 + r * 8] =
              f2bf(y0a[rt][n2][r] + dt * zz - dt3 * k1[rt][n2][r]);
        }

    // g3: k3 = g(u3); u4 = y0 + dt*(k1-k2+k3); fold y1, partial-fold y0; emit out[t]
    geval();
#pragma unroll
    for (int rt = 0; rt < 4; ++rt)
#pragma unroll
      for (int n2 = 0; n2 < 2; ++n2)
#pragma unroll
        for (int r = 0; r < 4; ++r) {
          float k3v = za[rt][n2][r];
          float a = k1[rt][n2][r], b = k2[rt][n2][r];
          float y0v = y0a[rt][n2][r];
          Au[abase[n2] + rt * 128 + r * 8] = f2bf(y0v + dt * (a - b + k3v));
          float ny1 = y1a[rt][n2][r] + dt * y0v + q8 * (a + 2.0f * b + k3v);
          y1a[rt][n2][r] = ny1;
          y0a[rt][n2][r] = y0v + e8 * (a + 3.0f * (b + k3v));
          if (cc[n2] < 100)
            out[obase[n2] + rt * 25600 + r * 1600 + t * 100] = ny1;
        }

    // g4: k4 = g(u4); y0 += dt/8*k4; write y0 as next step's u
    geval();
#pragma unroll
    for (int rt = 0; rt < 4; ++rt)
#pragma unroll
      for (int n2 = 0; n2 < 2; ++n2)
#pragma unroll
        for (int r = 0; r < 4; ++r) {
          float y0v = y0a[rt][n2][r] + e8 * za[rt][n2][r];
          y0a[rt][n2][r] = y0v;
          Au[abase[n2] + rt * 128 + r * 8] = f2bf(y0v);
        }
  }
}

extern "C" void kernel_launch(void* const* d_in, const int* in_sizes, int n_in,
                              void* d_out, int out_size, void* d_ws, size_t ws_size,
                              hipStream_t stream) {
  (void)in_sizes; (void)n_in; (void)out_size; (void)d_ws; (void)ws_size;
  const float* x    = (const float*)d_in[0];
  const float* W0   = (const float*)d_in[1];
  const float* b0   = (const float*)d_in[2];
  const float* W1   = (const float*)d_in[3];
  const float* b1   = (const float*)d_in[4];
  const float* Wode = (const float*)d_in[5];
  const float* bode = (const float*)d_in[6];
  float* out = (float*)d_out;

  dim3 grid(BATCH / 64), block(256);
  hipLaunchKernelGGL(node_kernel, grid, block, 0, stream,
                     x, W0, b0, W1, b1, Wode, bode, out);
}